// Round 7
// baseline (61.403 us; speedup 1.0000x reference)
//
#include <hip/hip_runtime.h>

// B=1024, A=256, E=4, M1=128, M2=16, H1=32, H2=64
#define XROW 1537
#define NTHR 512
#define SP   320              // padded slot space: 5 tiles x 64 (max St4 = 268)
#define RST  324              // RmT row stride: mod 32 == 4 -> conflict-free

// ws layout (floats): [0,128) Tsort[4][32]; [128,128+16896) AC[e][33][64][2]
// h2_pre[o] = v*A_k[o] + C_k[o] on interval k — exact piecewise-affine
// collapse of relu(v*W1+b1) @ W2 + b2 in the scalar v.

__global__ void __launch_bounds__(256)
be_prep(const float* __restrict__ W1, const float* __restrict__ b1,
        const float* __restrict__ W2, const float* __restrict__ b2,
        float* __restrict__ ws)
{
    __shared__ float t_s[4][32], w1_s[4][32], b1_s[4][32];
    __shared__ int   sidx[4][32];
    const int w = threadIdx.x >> 6, lane = threadIdx.x & 63;
    const int e = w;                       // one expert per wave

    if (lane < 32) {
        float w1v = W1[e * 32 + lane];
        float b1v = b1[e * 32 + lane];
        w1_s[e][lane] = w1v;
        b1_s[e][lane] = b1v;
        t_s[e][lane] = (w1v != 0.f) ? (-b1v / w1v) : 3.4e38f;
    }
    __syncthreads();
    if (lane < 32) {
        float ti = t_s[e][lane];
        int rank = 0;
        for (int j = 0; j < 32; ++j) {
            float tj = t_s[e][j];
            rank += (tj < ti) || (tj == ti && j < lane);
        }
        sidx[e][rank] = lane;
        ws[e * 32 + rank] = ti;            // sorted thresholds
    }
    __syncthreads();

    float* AC = ws + 128;
    const int o = lane;
    float A = 0.f, C = b2[e * 64 + o];
    for (int i = 0; i < 32; ++i) {         // active set at v = -inf
        float w1v = w1_s[e][i], b1v = b1_s[e][i];
        if ((w1v < 0.f) || (w1v == 0.f && b1v > 0.f)) {
            float w2v = W2[(e * 32 + i) * 64 + o];
            A = fmaf(w1v, w2v, A);
            C = fmaf(b1v, w2v, C);
        }
    }
    AC[(e * 33 + 0) * 128 + 2 * o]     = A;
    AC[(e * 33 + 0) * 128 + 2 * o + 1] = C;
    for (int k = 1; k <= 32; ++k) {
        int i = sidx[e][k - 1];
        float w1v = w1_s[e][i], b1v = b1_s[e][i];
        float w2v = W2[(e * 32 + i) * 64 + o];
        if (w1v > 0.f)      { A += w1v * w2v; C += b1v * w2v; }  // turns on
        else if (w1v < 0.f) { A -= w1v * w2v; C -= b1v * w2v; }  // turns off
        AC[(e * 33 + k) * 128 + 2 * o]     = A;
        AC[(e * 33 + k) * 128 + 2 * o + 1] = C;
    }
}

__global__ void __launch_bounds__(NTHR)
be_kernel(const float* __restrict__ x,
          const float* __restrict__ W3, const float* __restrict__ b3,
          const float* __restrict__ wsr,
          float* __restrict__ out)
{
    __shared__ float vca[SP];                       // compacted v (pads = 0)
    __shared__ __align__(16) float RmT[4][RST];     // [c][slot], mask folded
    __shared__ __align__(16) float H2T[64][68];     // [i][a_local], wave-owned rows
    __shared__ __align__(16) float S2[2][4][4][64]; // [half][e][c][i]
    __shared__ float Tpart[4][4][32];
    __shared__ float T16[16];
    __shared__ float Pp[2][128 * 5];                // P partials (expert-pairs)
    __shared__ float Ts_l[128];                     // sorted thresholds
    __shared__ int   kea[SP];                       // per-slot AC base offset
    __shared__ int   cntw[8][4];

    const int tid  = threadIdx.x;
    const int b    = blockIdx.x;
    const int lane = tid & 63;
    const int w    = tid >> 6;
    const long xb  = (long)b * XROW;
    const float* ACg = wsr + 128;

    // ---- per-a input (a = tid < 256) ----
    float v = 0.f;
    int e = -1;                                     // waves 4..7: no match
    float maskf = 0.f;
    if (tid < 256) {
        v = x[xb + 2 * tid];
        e = (int)x[xb + 2 * tid + 1];
        e = max(0, min(3, e));
        int N = (int)x[xb + 1536];
        maskf = (tid < N) ? 1.f : 0.f;
    }
    if (tid < 128) Ts_l[tid] = wsr[tid];

    // ---- ballot compaction (waves 4..7 contribute zero counts) ----
    unsigned long long mybal = 0ull;
    #pragma unroll
    for (int q = 0; q < 4; ++q) {
        unsigned long long bq = __ballot(e == q);
        if (lane == 0) cntw[w][q] = __popcll(bq);
        if (e == q) mybal = bq;
    }
    int rank = __popcll(mybal & ((1ull << lane) - 1ull));

    // zero padded arrays before scatter
    if (tid < SP) { vca[tid] = 0.f; kea[tid] = 0; }
    for (int idx = tid; idx < 4 * RST; idx += NTHR) (&RmT[0][0])[idx] = 0.f;
    __syncthreads();

    int c0 = cntw[0][0] + cntw[1][0] + cntw[2][0] + cntw[3][0];
    int c1 = cntw[0][1] + cntw[1][1] + cntw[2][1] + cntw[3][1];
    int c2_ = cntw[0][2] + cntw[1][2] + cntw[2][2] + cntw[3][2];
    int c3 = cntw[0][3] + cntw[1][3] + cntw[2][3] + cntw[3][3];
    const int B0 = 0;
    const int B1 = (B0 + c0 + 3) & ~3;
    const int B2 = (B1 + c1 + 3) & ~3;
    const int B3 = (B2 + c2_ + 3) & ~3;
    const int St4 = (B3 + c3 + 3) & ~3;             // <= 268 <= SP

    if (tid < 256) {
        int offw = 0;
        #pragma unroll
        for (int w2 = 0; w2 < 4; ++w2) if (w2 < w) offw += cntw[w2][e];
        int Bsel = (e == 0) ? B0 : ((e == 1) ? B1 : ((e == 2) ? B2 : B3));
        int ci = Bsel + offw + rank;
        vca[ci] = v;
        #pragma unroll
        for (int c = 0; c < 4; ++c)
            RmT[c][ci] = x[xb + 512 + 4 * tid + c] * maskf;
    }
    __syncthreads();

    // ---- interval index per slot (pads keep kea=0, harmless) ----
    if (tid < St4) {
        int ev = (tid >= B1) + (tid >= B2) + (tid >= B3);
        float va = vca[tid];
        const float* Ts = &Ts_l[ev * 32];
        int k = 0;
        #pragma unroll
        for (int st = 32; st >= 1; st >>= 1)
            if (k + st <= 32 && Ts[k + st - 1] <= va) k += st;
        kea[tid] = (ev * 33 + k) * 128;
    }

    // ---- T[e][c] = sum_a R_masked (boundary-bounded) ----
    {
        int te = tid >> 7, tc = (tid >> 5) & 3, tk = tid & 31;
        int s0 = (te == 0) ? B0 : ((te == 1) ? B1 : ((te == 2) ? B2 : B3));
        int s1 = (te == 0) ? B1 : ((te == 1) ? B2 : ((te == 2) ? B3 : St4));
        float ts = 0.f;
        for (int s = s0 + tk; s < s1; s += 32) ts += RmT[tc][s];
        Tpart[te][tc][tk] = ts;
    }
    __syncthreads();          // kea + Tpart visible to all
    if (tid < 16) {
        float t = 0.f;
        #pragma unroll
        for (int k = 0; k < 32; ++k) t += Tpart[tid >> 2][tid & 3][k];
        T16[tid] = t;         // wave 0 finishes this before its tile work ends
    }

    // ---- 5 tiles of 64, ZERO inner barriers: wave w owns H2T rows [8w,8w+8)
    float S4_0 = 0.f, S4_1 = 0.f, S4_2 = 0.f, S4_3 = 0.f;
    const int jrow  = (w << 3) + (lane >> 3);   // my H2T row (2a AND 2b)
    const int abase = (lane & 7) << 3;          // 2a: my 8-column strip
    const int cc    = (lane >> 1) & 3;          // 2b: c index
    const int hf    = lane & 1;                 // 2b: a-half

    for (int t = 0; t < 5; ++t) {
        const int t64 = t << 6;
        // --- 2a: rows [8w,8w+8): lane (j,p) computes H2T[8w+j][8p..8p+8) ---
        int   ke8[8];
        float va8[8];
        #pragma unroll
        for (int u = 0; u < 8; ++u) {
            ke8[u] = kea[t64 + abase + u];
            va8[u] = vca[t64 + abase + u];
        }
        float2 ac8[8];
        #pragma unroll
        for (int u = 0; u < 8; ++u)
            ac8[u] = *(const float2*)&ACg[ke8[u] + 2 * jrow];
        #pragma unroll
        for (int u = 0; u < 8; ++u)
            H2T[jrow][abase + u] = fmaxf(fmaf(va8[u], ac8[u].x, ac8[u].y), 0.f);

        // --- 2b: read ONLY my wave's rows (same-wave DS order => no barrier)
        const float4* Hrow = (const float4*)&H2T[jrow][hf * 32];
        const float4* Rrow = (const float4*)&RmT[cc][t64 + hf * 32];
        #pragma unroll
        for (int k = 0; k < 8; ++k) {
            float4 h4 = Hrow[k];
            float4 r4 = Rrow[k];
            float d = h4.x * r4.x;
            d = fmaf(h4.y, r4.y, d);
            d = fmaf(h4.z, r4.z, d);
            d = fmaf(h4.w, r4.w, d);
            int gs = t64 + hf * 32 + 4 * k;       // group start (4-aligned)
            int eg = (gs >= B1) + (gs >= B2) + (gs >= B3);
            S4_0 += (eg == 0) ? d : 0.f;
            S4_1 += (eg == 1) ? d : 0.f;
            S4_2 += (eg == 2) ? d : 0.f;
            S4_3 += (eg == 3) ? d : 0.f;
        }
    }

    // ---- write S partials (thread -> (hf, cc, i2=jrow) bijective) ----
    S2[hf][0][cc][jrow] = S4_0;
    S2[hf][1][cc][jrow] = S4_1;
    S2[hf][2][cc][jrow] = S4_2;
    S2[hf][3][cc][jrow] = S4_3;
    __syncthreads();

    // ---- P[m][c] = sum_{e,i} W3[e,i,m] S[e,i,c] + sum_e b3[e,m] T[e,c] ----
    {
        const int m  = tid & 127;
        const int cp = (tid >> 7) & 1;       // c pair {2cp, 2cp+1}
        const int ih = tid >> 8;             // expert pair {2ih, 2ih+1}
        float acc0 = 0.f, acc1 = 0.f;
        #pragma unroll
        for (int eo = 0; eo < 2; ++eo) {
            const int ee = ih * 2 + eo;
            const float* W3e = W3 + ee * 8192 + m;
            #pragma unroll 4
            for (int i4 = 0; i4 < 16; ++i4) {
                float4 sA0 = *(const float4*)&S2[0][ee][2 * cp][4 * i4];
                float4 sA1 = *(const float4*)&S2[1][ee][2 * cp][4 * i4];
                float4 sB0 = *(const float4*)&S2[0][ee][2 * cp + 1][4 * i4];
                float4 sB1 = *(const float4*)&S2[1][ee][2 * cp + 1][4 * i4];
                float4 sA; sA.x = sA0.x + sA1.x; sA.y = sA0.y + sA1.y;
                           sA.z = sA0.z + sA1.z; sA.w = sA0.w + sA1.w;
                float4 sB; sB.x = sB0.x + sB1.x; sB.y = sB0.y + sB1.y;
                           sB.z = sB0.z + sB1.z; sB.w = sB0.w + sB1.w;
                const float* wp = W3e + (i4 * 4) * 128;
                float w0 = wp[0], w1 = wp[128], w2 = wp[256], w3 = wp[384];
                acc0 = fmaf(w0, sA.x, acc0); acc0 = fmaf(w1, sA.y, acc0);
                acc0 = fmaf(w2, sA.z, acc0); acc0 = fmaf(w3, sA.w, acc0);
                acc1 = fmaf(w0, sB.x, acc1); acc1 = fmaf(w1, sB.y, acc1);
                acc1 = fmaf(w2, sB.z, acc1); acc1 = fmaf(w3, sB.w, acc1);
            }
            float b3v = b3[ee * 128 + m];
            acc0 = fmaf(b3v, T16[ee * 4 + 2 * cp], acc0);
            acc1 = fmaf(b3v, T16[ee * 4 + 2 * cp + 1], acc1);
        }
        Pp[ih][m * 5 + 2 * cp]     = acc0;
        Pp[ih][m * 5 + 2 * cp + 1] = acc1;
    }
    __syncthreads();

    // ---- D[m][n] = sum_c P[m][c] P[n][c]  (Q == P[:16,:]^T) ----
    float* outb = out + (long)b * 2048;
    #pragma unroll
    for (int r = 0; r < 4; ++r) {
        int o = r * 512 + tid;
        int m = o >> 4, n = o & 15;
        float d = 0.f;
        #pragma unroll
        for (int c = 0; c < 4; ++c) {
            float pm = Pp[0][m * 5 + c] + Pp[1][m * 5 + c];
            float pn = Pp[0][n * 5 + c] + Pp[1][n * 5 + c];
            d = fmaf(pm, pn, d);
        }
        outb[o] = d;
    }
}

extern "C" void kernel_launch(void* const* d_in, const int* in_sizes, int n_in,
                              void* d_out, int out_size, void* d_ws, size_t ws_size,
                              hipStream_t stream)
{
    const float* x  = (const float*)d_in[0];
    const float* W1 = (const float*)d_in[1];
    const float* b1 = (const float*)d_in[2];
    const float* W2 = (const float*)d_in[3];
    const float* b2 = (const float*)d_in[4];
    const float* W3 = (const float*)d_in[5];
    const float* b3 = (const float*)d_in[6];
    float* out = (float*)d_out;
    float* ws  = (float*)d_ws;       // needs 68096 bytes

    be_prep<<<1, 256, 0, stream>>>(W1, b1, W2, b2, ws);
    be_kernel<<<1024, NTHR, 0, stream>>>(x, W3, b3, ws, out);
}

// Round 9
// 54.496 us; speedup vs baseline: 1.1268x; 1.1268x over previous
//
#include <hip/hip_runtime.h>

// B=1024, A=256, E=4, M1=128, M2=16, H1=32, H2=64
#define XROW 1537
#define NTHR 256
#define SP   320              // padded slot space: 5 tiles x 64 (max St4 = 268)
#define RST  324              // RmT row stride: mod 32 == 4 -> conflict-free

// ws layout (floats): [0,128) Tsort[4][32]; [128,128+16896) AC[e][33][64][2]
// h2_pre[o] = v*A_k[o] + C_k[o] on interval k — exact piecewise-affine
// collapse of relu(v*W1+b1) @ W2 + b2 in the scalar v.

__global__ void __launch_bounds__(256)
be_prep(const float* __restrict__ W1, const float* __restrict__ b1,
        const float* __restrict__ W2, const float* __restrict__ b2,
        float* __restrict__ ws)
{
    __shared__ float t_s[4][32], w1_s[4][32], b1_s[4][32];
    __shared__ int   rnk[4][32];
    __shared__ float ACd[4][33][128];      // per-interval deltas
    const int tid = threadIdx.x;
    const int w = tid >> 6, lane = tid & 63;
    const int e = w;                       // one expert per wave

    if (lane < 32) {
        float w1v = W1[e * 32 + lane], b1v = b1[e * 32 + lane];
        w1_s[e][lane] = w1v;
        b1_s[e][lane] = b1v;
        t_s[e][lane] = (w1v != 0.f) ? (-b1v / w1v) : 3.4e38f;
    }
    for (int idx = tid; idx < 4 * 33 * 128; idx += 256)
        (&ACd[0][0][0])[idx] = 0.f;
    __syncthreads();
    if (lane < 32) {
        float ti = t_s[e][lane];
        int rank = 0;
        for (int j = 0; j < 32; ++j) {
            float tj = t_s[e][j];
            rank += (tj < ti) || (tj == ti && j < lane);
        }
        rnk[e][lane] = rank;
        ws[e * 32 + rank] = ti;            // sorted thresholds
    }
    __syncthreads();

    // base (v=-inf active set) + delta scatter; all W2 loads static-indexed
    const int o = lane;
    float A = 0.f, C = b2[e * 64 + o];
    #pragma unroll
    for (int i = 0; i < 32; ++i) {
        float w1v = w1_s[e][i], b1v = b1_s[e][i];
        float w2v = W2[(e * 32 + i) * 64 + o];       // static -> batched
        if ((w1v < 0.f) || (w1v == 0.f && b1v > 0.f)) {
            A = fmaf(w1v, w2v, A);
            C = fmaf(b1v, w2v, C);
        }
        if (w1v != 0.f) {
            int r = rnk[e][i];                       // unique rank per i
            float s = (w1v > 0.f) ? 1.f : -1.f;
            ACd[e][r + 1][2 * o]     = s * w1v * w2v;
            ACd[e][r + 1][2 * o + 1] = s * b1v * w2v;
        }
    }
    // prefix over k (same-lane LDS, in-order) + store
    float* AC = ws + 128;
    float2 p; p.x = A; p.y = C;
    *(float2*)&AC[(e * 33 + 0) * 128 + 2 * o] = p;
    for (int k = 1; k <= 32; ++k) {
        A += ACd[e][k][2 * o];
        C += ACd[e][k][2 * o + 1];
        p.x = A; p.y = C;
        *(float2*)&AC[(e * 33 + k) * 128 + 2 * o] = p;
    }
}

__global__ void __launch_bounds__(NTHR)
be_kernel(const float* __restrict__ x,
          const float* __restrict__ W3, const float* __restrict__ b3,
          const float* __restrict__ wsr,
          float* __restrict__ out)
{
    __shared__ float vca[SP];                       // compacted v (pads = 0)
    __shared__ __align__(16) float RmT[4][RST];     // [c][slot], mask folded
    __shared__ __align__(16) float H2T[64][68];     // [i][a_local]
    __shared__ __align__(16) float S_l[4][4][64];   // [e][c][i]
    __shared__ float Tpart[4][4][16];
    __shared__ float T16[16];
    __shared__ float Pr5[128 * 5];                  // P, stride 5
    __shared__ float Ts_l[128];                     // sorted thresholds
    __shared__ int   kea[SP];                       // per-slot AC base offset
    __shared__ int   cntw[4][4];

    const int tid  = threadIdx.x;
    const int b    = blockIdx.x;
    const int lane = tid & 63;
    const int w    = tid >> 6;
    const long xb  = (long)b * XROW;
    const float* ACg = wsr + 128;

    // ---- per-a input (a = tid) ----
    float v = x[xb + 2 * tid];
    int e = (int)x[xb + 2 * tid + 1];
    e = max(0, min(3, e));
    int N = (int)x[xb + 1536];
    float maskf = (tid < N) ? 1.f : 0.f;
    if (tid < 128) Ts_l[tid] = wsr[tid];

    // ---- ballot compaction (deterministic ranks) ----
    unsigned long long mybal = 0ull;
    #pragma unroll
    for (int q = 0; q < 4; ++q) {
        unsigned long long bq = __ballot(e == q);
        if (lane == 0) cntw[w][q] = __popcll(bq);
        if (e == q) mybal = bq;
    }
    int rank = __popcll(mybal & ((1ull << lane) - 1ull));

    // zero padded arrays before scatter
    for (int idx = tid; idx < SP; idx += NTHR) { vca[idx] = 0.f; kea[idx] = 0; }
    for (int idx = tid; idx < 4 * RST; idx += NTHR) (&RmT[0][0])[idx] = 0.f;
    __syncthreads();

    int c0 = cntw[0][0] + cntw[1][0] + cntw[2][0] + cntw[3][0];
    int c1 = cntw[0][1] + cntw[1][1] + cntw[2][1] + cntw[3][1];
    int c2_ = cntw[0][2] + cntw[1][2] + cntw[2][2] + cntw[3][2];
    int c3 = cntw[0][3] + cntw[1][3] + cntw[2][3] + cntw[3][3];
    const int B0 = 0;
    const int B1 = (B0 + c0 + 3) & ~3;
    const int B2 = (B1 + c1 + 3) & ~3;
    const int B3 = (B2 + c2_ + 3) & ~3;
    const int St4 = (B3 + c3 + 3) & ~3;             // <= 268 <= SP

    {
        int offw = 0;
        #pragma unroll
        for (int w2 = 0; w2 < 4; ++w2) if (w2 < w) offw += cntw[w2][e];
        int Bsel = (e == 0) ? B0 : ((e == 1) ? B1 : ((e == 2) ? B2 : B3));
        int ci = Bsel + offw + rank;
        vca[ci] = v;
        #pragma unroll
        for (int c = 0; c < 4; ++c)
            RmT[c][ci] = x[xb + 512 + 4 * tid + c] * maskf;
    }
    __syncthreads();

    // ---- interval index per slot; GRID-STRIDE: St4 may exceed NTHR! ----
    for (int a2 = tid; a2 < St4; a2 += NTHR) {
        int ev = (a2 >= B1) + (a2 >= B2) + (a2 >= B3);
        float va = vca[a2];
        const float* Ts = &Ts_l[ev * 32];
        int k = 0;
        #pragma unroll
        for (int st = 32; st >= 1; st >>= 1)
            if (k + st <= 32 && Ts[k + st - 1] <= va) k += st;
        kea[a2] = (ev * 33 + k) * 128;
    }

    // ---- T[e][c] = sum_a R_masked (boundary-bounded) ----
    {
        int te = tid >> 6, tc = (tid >> 4) & 3, tk = tid & 15;
        int s0 = (te == 0) ? B0 : ((te == 1) ? B1 : ((te == 2) ? B2 : B3));
        int s1 = (te == 0) ? B1 : ((te == 1) ? B2 : ((te == 2) ? B3 : St4));
        float ts = 0.f;
        for (int s = s0 + tk; s < s1; s += 16) ts += RmT[tc][s];
        Tpart[te][tc][tk] = ts;
    }
    __syncthreads();          // kea + Tpart visible to all
    if (tid < 16) {
        float t = 0.f;
        #pragma unroll
        for (int k = 0; k < 16; ++k) t += Tpart[tid >> 2][tid & 3][k];
        T16[tid] = t;         // consumed in phase 3, after tile-loop barriers
    }

    // ---- 5 tiles of 64: software-pipelined 2a (wave-uniform coalesced
    //      batched AC loads for t+1 issued before 2b of t), barriered 2b ----
    float S4_0 = 0.f, S4_1 = 0.f, S4_2 = 0.f, S4_3 = 0.f;
    const int i2 = tid >> 2, cc = tid & 3;
    const int aw = w << 4;                 // wave's 16-a strip base

    float2 ac16[16];
    float  va16[16];
    {   // prologue: tile 0
        #pragma unroll
        for (int u = 0; u < 16; ++u) va16[u] = vca[aw + u];
        int ke16[16];
        #pragma unroll
        for (int u = 0; u < 16; ++u) ke16[u] = kea[aw + u];
        #pragma unroll
        for (int u = 0; u < 16; ++u)
            ac16[u] = *(const float2*)&ACg[ke16[u] + 2 * lane];
    }

    #pragma unroll
    for (int t = 0; t < 5; ++t) {
        const int t64 = t << 6;
        // --- 2a: write H2T rows (lane = o), 4x ds_write_b128 ---
        #pragma unroll
        for (int u4 = 0; u4 < 4; ++u4) {
            float4 hq;
            hq.x = fmaxf(fmaf(va16[4*u4+0], ac16[4*u4+0].x, ac16[4*u4+0].y), 0.f);
            hq.y = fmaxf(fmaf(va16[4*u4+1], ac16[4*u4+1].x, ac16[4*u4+1].y), 0.f);
            hq.z = fmaxf(fmaf(va16[4*u4+2], ac16[4*u4+2].x, ac16[4*u4+2].y), 0.f);
            hq.w = fmaxf(fmaf(va16[4*u4+3], ac16[4*u4+3].x, ac16[4*u4+3].y), 0.f);
            *(float4*)&H2T[lane][aw + 4 * u4] = hq;
        }
        // --- prefetch tile t+1 (flies across both barriers + 2b) ---
        if (t < 4) {
            const int nb = ((t + 1) << 6) + aw;
            int ke16[16];
            #pragma unroll
            for (int u = 0; u < 16; ++u) { ke16[u] = kea[nb + u]; va16[u] = vca[nb + u]; }
            #pragma unroll
            for (int u = 0; u < 16; ++u)
                ac16[u] = *(const float2*)&ACg[ke16[u] + 2 * lane];
        }
        __syncthreads();
        // --- 2b: thread (i2, cc) over all 64 a of tile t ---
        const float4* Hrow = (const float4*)&H2T[i2][0];
        const float4* Rrow = (const float4*)&RmT[cc][t64];
        #pragma unroll
        for (int k = 0; k < 16; ++k) {
            float4 h4 = Hrow[k];
            float4 r4 = Rrow[k];
            float d = h4.x * r4.x;
            d = fmaf(h4.y, r4.y, d);
            d = fmaf(h4.z, r4.z, d);
            d = fmaf(h4.w, r4.w, d);
            int gs = t64 + 4 * k;                 // 4-aligned group
            int eg = (gs >= B1) + (gs >= B2) + (gs >= B3);
            S4_0 += (eg == 0) ? d : 0.f;
            S4_1 += (eg == 1) ? d : 0.f;
            S4_2 += (eg == 2) ? d : 0.f;
            S4_3 += (eg == 3) ? d : 0.f;
        }
        __syncthreads();
    }

    // ---- write S ----
    S_l[0][cc][i2] = S4_0;
    S_l[1][cc][i2] = S4_1;
    S_l[2][cc][i2] = S4_2;
    S_l[3][cc][i2] = S4_3;
    __syncthreads();

    // ---- P[m][c] = sum_{e,i} W3[e,i,m] S[e,i,c] + sum_e b3[e,m] T[e,c] ----
    {
        const int m  = tid & 127;
        const int cp = tid >> 7;                 // c pair {2cp, 2cp+1}
        float acc0 = 0.f, acc1 = 0.f;
        #pragma unroll
        for (int ee = 0; ee < 4; ++ee) {
            const float* W3e = W3 + ee * 8192 + m;
            #pragma unroll 4
            for (int i4 = 0; i4 < 16; ++i4) {
                const float4 sA = *(const float4*)&S_l[ee][2 * cp][4 * i4];
                const float4 sB = *(const float4*)&S_l[ee][2 * cp + 1][4 * i4];
                const float* wp = W3e + (i4 * 4) * 128;
                float w0 = wp[0], w1 = wp[128], w2 = wp[256], w3 = wp[384];
                acc0 = fmaf(w0, sA.x, acc0); acc0 = fmaf(w1, sA.y, acc0);
                acc0 = fmaf(w2, sA.z, acc0); acc0 = fmaf(w3, sA.w, acc0);
                acc1 = fmaf(w0, sB.x, acc1); acc1 = fmaf(w1, sB.y, acc1);
                acc1 = fmaf(w2, sB.z, acc1); acc1 = fmaf(w3, sB.w, acc1);
            }
            float b3v = b3[ee * 128 + m];
            acc0 = fmaf(b3v, T16[ee * 4 + 2 * cp], acc0);
            acc1 = fmaf(b3v, T16[ee * 4 + 2 * cp + 1], acc1);
        }
        Pr5[m * 5 + 2 * cp]     = acc0;
        Pr5[m * 5 + 2 * cp + 1] = acc1;
    }
    __syncthreads();

    // ---- D[m][n] = sum_c P[m][c] P[n][c]; 8 consecutive outputs/thread ----
    {
        const int m   = tid >> 1;
        const int nb8 = (tid & 1) << 3;
        float pm0 = Pr5[m * 5 + 0], pm1 = Pr5[m * 5 + 1];
        float pm2 = Pr5[m * 5 + 2], pm3 = Pr5[m * 5 + 3];
        float o8[8];
        #pragma unroll
        for (int r = 0; r < 8; ++r) {
            int n = nb8 + r;
            float d = pm0 * Pr5[n * 5 + 0];
            d = fmaf(pm1, Pr5[n * 5 + 1], d);
            d = fmaf(pm2, Pr5[n * 5 + 2], d);
            d = fmaf(pm3, Pr5[n * 5 + 3], d);
            o8[r] = d;
        }
        float* outb = out + (long)b * 2048 + tid * 8;
        float4 s0; s0.x = o8[0]; s0.y = o8[1]; s0.z = o8[2]; s0.w = o8[3];
        float4 s1; s1.x = o8[4]; s1.y = o8[5]; s1.z = o8[6]; s1.w = o8[7];
        *(float4*)&outb[0] = s0;
        *(float4*)&outb[4] = s1;
    }
}

extern "C" void kernel_launch(void* const* d_in, const int* in_sizes, int n_in,
                              void* d_out, int out_size, void* d_ws, size_t ws_size,
                              hipStream_t stream)
{
    const float* x  = (const float*)d_in[0];
    const float* W1 = (const float*)d_in[1];
    const float* b1 = (const float*)d_in[2];
    const float* W2 = (const float*)d_in[3];
    const float* b2 = (const float*)d_in[4];
    const float* W3 = (const float*)d_in[5];
    const float* b3 = (const float*)d_in[6];
    float* out = (float*)d_out;
    float* ws  = (float*)d_ws;       // needs 68096 bytes

    be_prep<<<1, 256, 0, stream>>>(W1, b1, W2, b2, ws);
    be_kernel<<<1024, NTHR, 0, stream>>>(x, W3, b3, ws, out);
}

// Round 10
// 54.478 us; speedup vs baseline: 1.1271x; 1.0003x over previous
//
#include <hip/hip_runtime.h>

// B=1024, A=256, E=4, M1=128, M2=16, H1=32, H2=64
#define XROW 1537
#define NTHR 256
#define SP   320              // padded slot space: 5 tiles x 64 (max St4 = 268)
#define RST  324              // RmT row stride: mod 32 == 4 -> conflict-free

// DS-only barrier: drains LDS counter + syncs waves but leaves global-load
// (vmcnt) traffic in flight across the barrier (hipcc's __syncthreads would
// drain vmcnt(0) and kill the software pipeline).
#define BAR_DS() asm volatile("s_waitcnt lgkmcnt(0)\n\ts_barrier" ::: "memory")

// ws layout (floats): [0,128) Tsort[4][32]; [128,128+16896) AC[e][33][64][2]
// h2_pre[o] = v*A_k[o] + C_k[o] on interval k — exact piecewise-affine
// collapse of relu(v*W1+b1) @ W2 + b2 in the scalar v.

__global__ void __launch_bounds__(256)
be_prep(const float* __restrict__ W1, const float* __restrict__ b1,
        const float* __restrict__ W2, const float* __restrict__ b2,
        float* __restrict__ ws)
{
    __shared__ float t_s[4][32], w1_s[4][32], b1_s[4][32];
    __shared__ int   rnk[4][32];
    __shared__ float ACd[4][33][128];      // per-interval deltas
    const int tid = threadIdx.x;
    const int w = tid >> 6, lane = tid & 63;
    const int e = w;                       // one expert per wave

    if (lane < 32) {
        float w1v = W1[e * 32 + lane], b1v = b1[e * 32 + lane];
        w1_s[e][lane] = w1v;
        b1_s[e][lane] = b1v;
        t_s[e][lane] = (w1v != 0.f) ? (-b1v / w1v) : 3.4e38f;
    }
    for (int idx = tid; idx < 4 * 33 * 128; idx += 256)
        (&ACd[0][0][0])[idx] = 0.f;
    __syncthreads();
    if (lane < 32) {
        float ti = t_s[e][lane];
        int rank = 0;
        for (int j = 0; j < 32; ++j) {
            float tj = t_s[e][j];
            rank += (tj < ti) || (tj == ti && j < lane);
        }
        rnk[e][lane] = rank;
        ws[e * 32 + rank] = ti;            // sorted thresholds
    }
    __syncthreads();

    // base (v=-inf active set) + delta scatter; all W2 loads static-indexed
    const int o = lane;
    float A = 0.f, C = b2[e * 64 + o];
    #pragma unroll
    for (int i = 0; i < 32; ++i) {
        float w1v = w1_s[e][i], b1v = b1_s[e][i];
        float w2v = W2[(e * 32 + i) * 64 + o];       // static -> batched
        if ((w1v < 0.f) || (w1v == 0.f && b1v > 0.f)) {
            A = fmaf(w1v, w2v, A);
            C = fmaf(b1v, w2v, C);
        }
        if (w1v != 0.f) {
            int r = rnk[e][i];                       // unique rank per i
            float s = (w1v > 0.f) ? 1.f : -1.f;
            ACd[e][r + 1][2 * o]     = s * w1v * w2v;
            ACd[e][r + 1][2 * o + 1] = s * b1v * w2v;
        }
    }
    // prefix over k (same-lane LDS, in-order) + store
    float* AC = ws + 128;
    float2 p; p.x = A; p.y = C;
    *(float2*)&AC[(e * 33 + 0) * 128 + 2 * o] = p;
    for (int k = 1; k <= 32; ++k) {
        A += ACd[e][k][2 * o];
        C += ACd[e][k][2 * o + 1];
        p.x = A; p.y = C;
        *(float2*)&AC[(e * 33 + k) * 128 + 2 * o] = p;
    }
}

__global__ void __launch_bounds__(NTHR)
be_kernel(const float* __restrict__ x,
          const float* __restrict__ W3, const float* __restrict__ b3,
          const float* __restrict__ wsr,
          float* __restrict__ out)
{
    __shared__ float vca[SP];                       // compacted v (pads = 0)
    __shared__ __align__(16) float RmT[4][RST];     // [c][slot], mask folded
    __shared__ __align__(16) float H2T[64][68];     // [i][a_local]
    __shared__ __align__(16) float S_l[4][4][64];   // [e][c][i]
    __shared__ float Tpart[4][4][16];
    __shared__ float T16[16];
    __shared__ float Pr5[128 * 5];                  // P, stride 5
    __shared__ float Ts_l[128];                     // sorted thresholds
    __shared__ int   kea[SP];                       // per-slot AC base offset
    __shared__ int   cntw[4][4];

    const int tid  = threadIdx.x;
    const int b    = blockIdx.x;
    const int lane = tid & 63;
    const int w    = tid >> 6;
    const long xb  = (long)b * XROW;
    const float* ACg = wsr + 128;

    // ---- per-a input (a = tid) ----
    float v = x[xb + 2 * tid];
    int e = (int)x[xb + 2 * tid + 1];
    e = max(0, min(3, e));
    int N = (int)x[xb + 1536];
    float maskf = (tid < N) ? 1.f : 0.f;
    if (tid < 128) Ts_l[tid] = wsr[tid];

    // ---- ballot compaction (deterministic ranks) ----
    unsigned long long mybal = 0ull;
    #pragma unroll
    for (int q = 0; q < 4; ++q) {
        unsigned long long bq = __ballot(e == q);
        if (lane == 0) cntw[w][q] = __popcll(bq);
        if (e == q) mybal = bq;
    }
    int rank = __popcll(mybal & ((1ull << lane) - 1ull));

    // zero padded arrays before scatter
    for (int idx = tid; idx < SP; idx += NTHR) { vca[idx] = 0.f; kea[idx] = 0; }
    for (int idx = tid; idx < 4 * RST; idx += NTHR) (&RmT[0][0])[idx] = 0.f;
    __syncthreads();

    int c0 = cntw[0][0] + cntw[1][0] + cntw[2][0] + cntw[3][0];
    int c1 = cntw[0][1] + cntw[1][1] + cntw[2][1] + cntw[3][1];
    int c2_ = cntw[0][2] + cntw[1][2] + cntw[2][2] + cntw[3][2];
    int c3 = cntw[0][3] + cntw[1][3] + cntw[2][3] + cntw[3][3];
    const int B0 = 0;
    const int B1 = (B0 + c0 + 3) & ~3;
    const int B2 = (B1 + c1 + 3) & ~3;
    const int B3 = (B2 + c2_ + 3) & ~3;
    const int St4 = (B3 + c3 + 3) & ~3;             // <= 268 <= SP

    {
        int offw = 0;
        #pragma unroll
        for (int w2 = 0; w2 < 4; ++w2) if (w2 < w) offw += cntw[w2][e];
        int Bsel = (e == 0) ? B0 : ((e == 1) ? B1 : ((e == 2) ? B2 : B3));
        int ci = Bsel + offw + rank;
        vca[ci] = v;
        #pragma unroll
        for (int c = 0; c < 4; ++c)
            RmT[c][ci] = x[xb + 512 + 4 * tid + c] * maskf;
    }
    __syncthreads();

    // ---- interval index per slot; GRID-STRIDE: St4 may exceed NTHR! ----
    for (int a2 = tid; a2 < St4; a2 += NTHR) {
        int ev = (a2 >= B1) + (a2 >= B2) + (a2 >= B3);
        float va = vca[a2];
        const float* Ts = &Ts_l[ev * 32];
        int k = 0;
        #pragma unroll
        for (int st = 32; st >= 1; st >>= 1)
            if (k + st <= 32 && Ts[k + st - 1] <= va) k += st;
        kea[a2] = (ev * 33 + k) * 128;
    }

    // ---- T[e][c] = sum_a R_masked (boundary-bounded) ----
    {
        int te = tid >> 6, tc = (tid >> 4) & 3, tk = tid & 15;
        int s0 = (te == 0) ? B0 : ((te == 1) ? B1 : ((te == 2) ? B2 : B3));
        int s1 = (te == 0) ? B1 : ((te == 1) ? B2 : ((te == 2) ? B3 : St4));
        float ts = 0.f;
        for (int s = s0 + tk; s < s1; s += 16) ts += RmT[tc][s];
        Tpart[te][tc][tk] = ts;
    }
    __syncthreads();          // kea + Tpart visible to all
    if (tid < 16) {
        float t = 0.f;
        #pragma unroll
        for (int k = 0; k < 16; ++k) t += Tpart[tid >> 2][tid & 3][k];
        T16[tid] = t;         // consumed in phase 3, after tile-loop barriers
    }

    // ---- 5 tiles of 64: software-pipelined 2a; DS-only barriers keep the
    //      prefetched AC loads (vmcnt) in flight across the whole 2b phase ----
    float S4_0 = 0.f, S4_1 = 0.f, S4_2 = 0.f, S4_3 = 0.f;
    const int i2 = tid >> 2, cc = tid & 3;
    const int aw = w << 4;                 // wave's 16-a strip base

    float2 ac16[16];
    float  va16[16];
    {   // prologue: tile 0
        #pragma unroll
        for (int u = 0; u < 16; ++u) va16[u] = vca[aw + u];
        int ke16[16];
        #pragma unroll
        for (int u = 0; u < 16; ++u) ke16[u] = kea[aw + u];
        #pragma unroll
        for (int u = 0; u < 16; ++u)
            ac16[u] = *(const float2*)&ACg[ke16[u] + 2 * lane];
    }

    #pragma unroll
    for (int t = 0; t < 5; ++t) {
        const int t64 = t << 6;
        // --- 2a: write H2T rows (lane = o), 4x ds_write_b128 ---
        #pragma unroll
        for (int u4 = 0; u4 < 4; ++u4) {
            float4 hq;
            hq.x = fmaxf(fmaf(va16[4*u4+0], ac16[4*u4+0].x, ac16[4*u4+0].y), 0.f);
            hq.y = fmaxf(fmaf(va16[4*u4+1], ac16[4*u4+1].x, ac16[4*u4+1].y), 0.f);
            hq.z = fmaxf(fmaf(va16[4*u4+2], ac16[4*u4+2].x, ac16[4*u4+2].y), 0.f);
            hq.w = fmaxf(fmaf(va16[4*u4+3], ac16[4*u4+3].x, ac16[4*u4+3].y), 0.f);
            *(float4*)&H2T[lane][aw + 4 * u4] = hq;
        }
        // --- prefetch tile t+1: issued here, waited only at next tile's 2a ---
        if (t < 4) {
            const int nb = ((t + 1) << 6) + aw;
            int ke16[16];
            #pragma unroll
            for (int u = 0; u < 16; ++u) { ke16[u] = kea[nb + u]; va16[u] = vca[nb + u]; }
            #pragma unroll
            for (int u = 0; u < 16; ++u)
                ac16[u] = *(const float2*)&ACg[ke16[u] + 2 * lane];
        }
        BAR_DS();             // H2T visible; AC prefetch stays in flight
        // --- 2b: thread (i2, cc) over all 64 a of tile t ---
        const float4* Hrow = (const float4*)&H2T[i2][0];
        const float4* Rrow = (const float4*)&RmT[cc][t64];
        #pragma unroll
        for (int k = 0; k < 16; ++k) {
            float4 h4 = Hrow[k];
            float4 r4 = Rrow[k];
            float d = h4.x * r4.x;
            d = fmaf(h4.y, r4.y, d);
            d = fmaf(h4.z, r4.z, d);
            d = fmaf(h4.w, r4.w, d);
            int gs = t64 + 4 * k;                 // 4-aligned group
            int eg = (gs >= B1) + (gs >= B2) + (gs >= B3);
            S4_0 += (eg == 0) ? d : 0.f;
            S4_1 += (eg == 1) ? d : 0.f;
            S4_2 += (eg == 2) ? d : 0.f;
            S4_3 += (eg == 3) ? d : 0.f;
        }
        BAR_DS();             // 2b reads done before next tile's H2T writes
    }

    // ---- write S ----
    S_l[0][cc][i2] = S4_0;
    S_l[1][cc][i2] = S4_1;
    S_l[2][cc][i2] = S4_2;
    S_l[3][cc][i2] = S4_3;
    __syncthreads();

    // ---- P[m][c] = sum_{e,i} W3[e,i,m] S[e,i,c] + sum_e b3[e,m] T[e,c] ----
    {
        const int m  = tid & 127;
        const int cp = tid >> 7;                 // c pair {2cp, 2cp+1}
        float acc0 = 0.f, acc1 = 0.f;
        #pragma unroll
        for (int ee = 0; ee < 4; ++ee) {
            const float* W3e = W3 + ee * 8192 + m;
            #pragma unroll 4
            for (int i4 = 0; i4 < 16; ++i4) {
                const float4 sA = *(const float4*)&S_l[ee][2 * cp][4 * i4];
                const float4 sB = *(const float4*)&S_l[ee][2 * cp + 1][4 * i4];
                const float* wp = W3e + (i4 * 4) * 128;
                float w0 = wp[0], w1 = wp[128], w2 = wp[256], w3 = wp[384];
                acc0 = fmaf(w0, sA.x, acc0); acc0 = fmaf(w1, sA.y, acc0);
                acc0 = fmaf(w2, sA.z, acc0); acc0 = fmaf(w3, sA.w, acc0);
                acc1 = fmaf(w0, sB.x, acc1); acc1 = fmaf(w1, sB.y, acc1);
                acc1 = fmaf(w2, sB.z, acc1); acc1 = fmaf(w3, sB.w, acc1);
            }
            float b3v = b3[ee * 128 + m];
            acc0 = fmaf(b3v, T16[ee * 4 + 2 * cp], acc0);
            acc1 = fmaf(b3v, T16[ee * 4 + 2 * cp + 1], acc1);
        }
        Pr5[m * 5 + 2 * cp]     = acc0;
        Pr5[m * 5 + 2 * cp + 1] = acc1;
    }
    __syncthreads();

    // ---- D[m][n] = sum_c P[m][c] P[n][c]; 8 consecutive outputs/thread ----
    {
        const int m   = tid >> 1;
        const int nb8 = (tid & 1) << 3;
        float pm0 = Pr5[m * 5 + 0], pm1 = Pr5[m * 5 + 1];
        float pm2 = Pr5[m * 5 + 2], pm3 = Pr5[m * 5 + 3];
        float o8[8];
        #pragma unroll
        for (int r = 0; r < 8; ++r) {
            int n = nb8 + r;
            float d = pm0 * Pr5[n * 5 + 0];
            d = fmaf(pm1, Pr5[n * 5 + 1], d);
            d = fmaf(pm2, Pr5[n * 5 + 2], d);
            d = fmaf(pm3, Pr5[n * 5 + 3], d);
            o8[r] = d;
        }
        float* outb = out + (long)b * 2048 + tid * 8;
        float4 s0; s0.x = o8[0]; s0.y = o8[1]; s0.z = o8[2]; s0.w = o8[3];
        float4 s1; s1.x = o8[4]; s1.y = o8[5]; s1.z = o8[6]; s1.w = o8[7];
        *(float4*)&outb[0] = s0;
        *(float4*)&outb[4] = s1;
    }
}

extern "C" void kernel_launch(void* const* d_in, const int* in_sizes, int n_in,
                              void* d_out, int out_size, void* d_ws, size_t ws_size,
                              hipStream_t stream)
{
    const float* x  = (const float*)d_in[0];
    const float* W1 = (const float*)d_in[1];
    const float* b1 = (const float*)d_in[2];
    const float* W2 = (const float*)d_in[3];
    const float* b2 = (const float*)d_in[4];
    const float* W3 = (const float*)d_in[5];
    const float* b3 = (const float*)d_in[6];
    float* out = (float*)d_out;
    float* ws  = (float*)d_ws;       // needs 68096 bytes

    be_prep<<<1, 256, 0, stream>>>(W1, b1, W2, b2, ws);
    be_kernel<<<1024, NTHR, 0, stream>>>(x, W3, b3, ws, out);
}

// Round 11
// 37.764 us; speedup vs baseline: 1.6260x; 1.4426x over previous
//
#include <hip/hip_runtime.h>

// B=1024, A=256, E=4, M1=128, M2=16, H1=32, H2=64
#define XROW 1537
#define NTHR 256
#define SP   320              // padded slot space: 5 strips-of-64 (max St4 = 268)

// ws layout (floats): [0,128) Tsort[4][32]; [128,128+16896) AC[e][33][64][2]
// h2_pre[o] = v*A_k[o] + C_k[o] on interval k — exact piecewise-affine
// collapse of relu(v*W1+b1) @ W2 + b2 in the scalar v.

__device__ __forceinline__ float rlf(float x, int u) {
    return __uint_as_float(__builtin_amdgcn_readlane(__float_as_uint(x), u));
}
__device__ __forceinline__ int rli(int x, int u) {
    return __builtin_amdgcn_readlane(x, u);
}

__global__ void __launch_bounds__(256)
be_prep(const float* __restrict__ W1, const float* __restrict__ b1,
        const float* __restrict__ W2, const float* __restrict__ b2,
        float* __restrict__ ws)
{
    __shared__ float t_s[4][32], w1_s[4][32], b1_s[4][32];
    __shared__ int   rnk[4][32];
    __shared__ float ACd[4][33][128];      // per-interval deltas
    const int tid = threadIdx.x;
    const int w = tid >> 6, lane = tid & 63;
    const int e = w;                       // one expert per wave

    if (lane < 32) {
        float w1v = W1[e * 32 + lane], b1v = b1[e * 32 + lane];
        w1_s[e][lane] = w1v;
        b1_s[e][lane] = b1v;
        t_s[e][lane] = (w1v != 0.f) ? (-b1v / w1v) : 3.4e38f;
    }
    for (int idx = tid; idx < 4 * 33 * 128; idx += 256)
        (&ACd[0][0][0])[idx] = 0.f;
    __syncthreads();
    if (lane < 32) {
        float ti = t_s[e][lane];
        int rank = 0;
        for (int j = 0; j < 32; ++j) {
            float tj = t_s[e][j];
            rank += (tj < ti) || (tj == ti && j < lane);
        }
        rnk[e][lane] = rank;
        ws[e * 32 + rank] = ti;            // sorted thresholds
    }
    __syncthreads();

    // base (v=-inf active set) + delta scatter; all W2 loads static-indexed
    const int o = lane;
    float A = 0.f, C = b2[e * 64 + o];
    #pragma unroll
    for (int i = 0; i < 32; ++i) {
        float w1v = w1_s[e][i], b1v = b1_s[e][i];
        float w2v = W2[(e * 32 + i) * 64 + o];
        if ((w1v < 0.f) || (w1v == 0.f && b1v > 0.f)) {
            A = fmaf(w1v, w2v, A);
            C = fmaf(b1v, w2v, C);
        }
        if (w1v != 0.f) {
            int r = rnk[e][i];
            float s = (w1v > 0.f) ? 1.f : -1.f;
            ACd[e][r + 1][2 * o]     = s * w1v * w2v;
            ACd[e][r + 1][2 * o + 1] = s * b1v * w2v;
        }
    }
    float* AC = ws + 128;
    float2 p; p.x = A; p.y = C;
    *(float2*)&AC[(e * 33 + 0) * 128 + 2 * o] = p;
    for (int k = 1; k <= 32; ++k) {
        A += ACd[e][k][2 * o];
        C += ACd[e][k][2 * o + 1];
        p.x = A; p.y = C;
        *(float2*)&AC[(e * 33 + k) * 128 + 2 * o] = p;
    }
}

__global__ void __launch_bounds__(NTHR)
be_kernel(const float* __restrict__ x,
          const float* __restrict__ W3, const float* __restrict__ b3,
          const float* __restrict__ wsr,
          float* __restrict__ out)
{
    __shared__ int2   kv[SP];                     // {kea, bits(va)}, pads = 0
    __shared__ __align__(16) float4 Rm4[SP];      // [slot] -> R[0..3], masked
    __shared__ float Ts_l[128];                   // sorted thresholds
    __shared__ __align__(16) float Spart[4][4][64][4];  // [w][e][o][c]
    __shared__ __align__(16) float Sred[4][64][4];      // [e][i][c]
    __shared__ __align__(16) float Pp[4][128][4];       // [w=ee][m][c]
    __shared__ float Pr5[128 * 5];
    __shared__ float Tpart[4][4][16];
    __shared__ float T16[16];
    __shared__ int   cntw[4][4];

    const int tid  = threadIdx.x;
    const int b    = blockIdx.x;
    const int lane = tid & 63;
    const int w    = tid >> 6;
    const long xb  = (long)b * XROW;
    const float* ACg = wsr + 128;

    // ---- per-a input (a = tid) ----
    float v = x[xb + 2 * tid];
    int e = (int)x[xb + 2 * tid + 1];
    e = max(0, min(3, e));
    int N = (int)x[xb + 1536];
    float maskf = (tid < N) ? 1.f : 0.f;
    if (tid < 128) Ts_l[tid] = wsr[tid];

    // ---- ballot compaction (deterministic ranks) ----
    unsigned long long mybal = 0ull;
    #pragma unroll
    for (int q = 0; q < 4; ++q) {
        unsigned long long bq = __ballot(e == q);
        if (lane == 0) cntw[w][q] = __popcll(bq);
        if (e == q) mybal = bq;
    }
    int rank = __popcll(mybal & ((1ull << lane) - 1ull));

    // zero padded tables
    for (int idx = tid; idx < SP; idx += NTHR) {
        kv[idx] = make_int2(0, 0);
        Rm4[idx] = make_float4(0.f, 0.f, 0.f, 0.f);
    }
    __syncthreads();

    int c0 = cntw[0][0] + cntw[1][0] + cntw[2][0] + cntw[3][0];
    int c1 = cntw[0][1] + cntw[1][1] + cntw[2][1] + cntw[3][1];
    int c2_ = cntw[0][2] + cntw[1][2] + cntw[2][2] + cntw[3][2];
    int c3 = cntw[0][3] + cntw[1][3] + cntw[2][3] + cntw[3][3];
    const int B0 = 0;
    const int B1 = (B0 + c0 + 3) & ~3;
    const int B2 = (B1 + c1 + 3) & ~3;
    const int B3 = (B2 + c2_ + 3) & ~3;
    const int St4 = (B3 + c3 + 3) & ~3;             // <= 268 <= SP

    {
        int offw = 0;
        #pragma unroll
        for (int w2 = 0; w2 < 4; ++w2) if (w2 < w) offw += cntw[w2][e];
        int Bsel = (e == 0) ? B0 : ((e == 1) ? B1 : ((e == 2) ? B2 : B3));
        int ci = Bsel + offw + rank;
        kv[ci] = make_int2(0, __float_as_int(v));   // kea filled next phase
        float4 r4;
        r4.x = x[xb + 512 + 4 * tid + 0] * maskf;
        r4.y = x[xb + 512 + 4 * tid + 1] * maskf;
        r4.z = x[xb + 512 + 4 * tid + 2] * maskf;
        r4.w = x[xb + 512 + 4 * tid + 3] * maskf;
        Rm4[ci] = r4;
    }
    __syncthreads();

    // ---- interval index per slot (pads keep kea=0: harmless, R=0) ----
    for (int a2 = tid; a2 < St4; a2 += NTHR) {
        int ev = (a2 >= B1) + (a2 >= B2) + (a2 >= B3);
        float va = __int_as_float(kv[a2].y);
        const float* Ts = &Ts_l[ev * 32];
        int k = 0;
        #pragma unroll
        for (int st = 32; st >= 1; st >>= 1)
            if (k + st <= 32 && Ts[k + st - 1] <= va) k += st;
        kv[a2].x = (ev * 33 + k) * 128;
    }

    // ---- T[e][c] = sum_a R_masked ----
    {
        int te = tid >> 6, tc = (tid >> 4) & 3, tk = tid & 15;
        int s0 = (te == 0) ? B0 : ((te == 1) ? B1 : ((te == 2) ? B2 : B3));
        int s1 = (te == 0) ? B1 : ((te == 1) ? B2 : ((te == 2) ? B3 : St4));
        float ts = 0.f;
        for (int s = s0 + tk; s < s1; s += 16) ts += ((const float*)&Rm4[s])[tc];
        Tpart[te][tc][tk] = ts;
    }
    __syncthreads();          // kv.x + Tpart visible to all
    if (tid < 16) {
        float t = 0.f;
        #pragma unroll
        for (int k = 0; k < 16; ++k) t += Tpart[tid >> 2][tid & 3][k];
        T16[tid] = t;         // consumed in P phase (after Spart barrier)
    }

    // ---- barrier-free S accumulation: wave w owns strips {t*64 + w*16} ----
    // lane = o (h2 output index). Per strip: 1 b64 + 1 b128 LDS gather,
    // readlane broadcasts (VALU, off the LDS pipe), 16 coalesced AC loads.
    float Se[4][4];           // [expert][c] accumulators, static indexed
    #pragma unroll
    for (int i = 0; i < 4; ++i)
        #pragma unroll
        for (int j = 0; j < 4; ++j) Se[i][j] = 0.f;

    #pragma unroll
    for (int t = 0; t < 5; ++t) {
        const int base = t * 64 + w * 16;
        int2   kvu = kv[base + (lane & 15)];     // lanes replicate 16 slots
        float4 r4u = Rm4[base + (lane & 15)];

        float2 ac16[16];
        #pragma unroll
        for (int u = 0; u < 16; ++u) {
            int s_k = rli(kvu.x, u);             // SGPR: coalesced saddr load
            ac16[u] = *(const float2*)&ACg[s_k + 2 * lane];
        }
        #pragma unroll
        for (int g = 0; g < 4; ++g) {            // 4-aligned, expert-pure groups
            float t0 = 0.f, t1 = 0.f, t2 = 0.f, t3 = 0.f;
            #pragma unroll
            for (int u4 = 0; u4 < 4; ++u4) {
                const int u = g * 4 + u4;
                float s_v = rlf(__int_as_float(kvu.y), u);
                float h = fmaxf(fmaf(s_v, ac16[u].x, ac16[u].y), 0.f);
                t0 = fmaf(h, rlf(r4u.x, u), t0);
                t1 = fmaf(h, rlf(r4u.y, u), t1);
                t2 = fmaf(h, rlf(r4u.z, u), t2);
                t3 = fmaf(h, rlf(r4u.w, u), t3);
            }
            const int gb = base + g * 4;
            const int eg = (gb >= B1) + (gb >= B2) + (gb >= B3);
            #pragma unroll
            for (int ee = 0; ee < 4; ++ee) {
                float fe = (eg == ee) ? 1.f : 0.f;   // scalar cselect
                Se[ee][0] = fmaf(t0, fe, Se[ee][0]);
                Se[ee][1] = fmaf(t1, fe, Se[ee][1]);
                Se[ee][2] = fmaf(t2, fe, Se[ee][2]);
                Se[ee][3] = fmaf(t3, fe, Se[ee][3]);
            }
        }
    }
    #pragma unroll
    for (int ee = 0; ee < 4; ++ee) {
        float4 s4; s4.x = Se[ee][0]; s4.y = Se[ee][1];
                   s4.z = Se[ee][2]; s4.w = Se[ee][3];
        *(float4*)&Spart[w][ee][lane][0] = s4;
    }
    __syncthreads();

    // ---- reduce Spart over waves: thread (e,i) ----
    {
        const int e_ = tid >> 6, i_ = tid & 63;
        float4 s0 = *(const float4*)&Spart[0][e_][i_][0];
        float4 s1 = *(const float4*)&Spart[1][e_][i_][0];
        float4 s2 = *(const float4*)&Spart[2][e_][i_][0];
        float4 s3 = *(const float4*)&Spart[3][e_][i_][0];
        float4 r; r.x = (s0.x + s1.x) + (s2.x + s3.x);
                  r.y = (s0.y + s1.y) + (s2.y + s3.y);
                  r.z = (s0.z + s1.z) + (s2.z + s3.z);
                  r.w = (s0.w + s1.w) + (s2.w + s3.w);
        *(float4*)&Sred[e_][i_][0] = r;
    }
    __syncthreads();

    // ---- P partials: wave w = expert; lane m-pair {lane, lane+64} ----
    {
        float a0 = 0.f, a1 = 0.f, a2 = 0.f, a3 = 0.f;   // m = lane
        float b0 = 0.f, b1_ = 0.f, b2_ = 0.f, b3_ = 0.f; // m = lane+64
        const float* W3e = W3 + w * 8192;
        #pragma unroll 8
        for (int i = 0; i < 64; ++i) {
            const float4 s4 = *(const float4*)&Sred[w][i][0];  // broadcast
            float wa = W3e[i * 128 + lane];
            float wb = W3e[i * 128 + 64 + lane];
            a0 = fmaf(wa, s4.x, a0); a1 = fmaf(wa, s4.y, a1);
            a2 = fmaf(wa, s4.z, a2); a3 = fmaf(wa, s4.w, a3);
            b0 = fmaf(wb, s4.x, b0); b1_ = fmaf(wb, s4.y, b1_);
            b2_ = fmaf(wb, s4.z, b2_); b3_ = fmaf(wb, s4.w, b3_);
        }
        const float4 t4 = *(const float4*)&T16[w * 4];
        float bya = b3[w * 128 + lane];
        float byb = b3[w * 128 + 64 + lane];
        a0 = fmaf(bya, t4.x, a0); a1 = fmaf(bya, t4.y, a1);
        a2 = fmaf(bya, t4.z, a2); a3 = fmaf(bya, t4.w, a3);
        b0 = fmaf(byb, t4.x, b0); b1_ = fmaf(byb, t4.y, b1_);
        b2_ = fmaf(byb, t4.z, b2_); b3_ = fmaf(byb, t4.w, b3_);
        float4 pa; pa.x = a0; pa.y = a1; pa.z = a2; pa.w = a3;
        float4 pb; pb.x = b0; pb.y = b1_; pb.z = b2_; pb.w = b3_;
        *(float4*)&Pp[w][lane][0]      = pa;
        *(float4*)&Pp[w][lane + 64][0] = pb;
    }
    __syncthreads();

    // ---- reduce Pp over experts -> Pr5 ----
    {
        const int m = tid >> 1, cp = tid & 1;
        float2 p0 = *(const float2*)&Pp[0][m][2 * cp];
        float2 p1 = *(const float2*)&Pp[1][m][2 * cp];
        float2 p2 = *(const float2*)&Pp[2][m][2 * cp];
        float2 p3 = *(const float2*)&Pp[3][m][2 * cp];
        Pr5[m * 5 + 2 * cp]     = (p0.x + p1.x) + (p2.x + p3.x);
        Pr5[m * 5 + 2 * cp + 1] = (p0.y + p1.y) + (p2.y + p3.y);
    }
    __syncthreads();

    // ---- D[m][n] = sum_c P[m][c] P[n][c]; 8 consecutive outputs/thread ----
    {
        const int m   = tid >> 1;
        const int nb8 = (tid & 1) << 3;
        float pm0 = Pr5[m * 5 + 0], pm1 = Pr5[m * 5 + 1];
        float pm2 = Pr5[m * 5 + 2], pm3 = Pr5[m * 5 + 3];
        float o8[8];
        #pragma unroll
        for (int r = 0; r < 8; ++r) {
            int n = nb8 + r;
            float d = pm0 * Pr5[n * 5 + 0];
            d = fmaf(pm1, Pr5[n * 5 + 1], d);
            d = fmaf(pm2, Pr5[n * 5 + 2], d);
            d = fmaf(pm3, Pr5[n * 5 + 3], d);
            o8[r] = d;
        }
        float* outb = out + (long)b * 2048 + tid * 8;
        float4 s0; s0.x = o8[0]; s0.y = o8[1]; s0.z = o8[2]; s0.w = o8[3];
        float4 s1; s1.x = o8[4]; s1.y = o8[5]; s1.z = o8[6]; s1.w = o8[7];
        *(float4*)&outb[0] = s0;
        *(float4*)&outb[4] = s1;
    }
}

extern "C" void kernel_launch(void* const* d_in, const int* in_sizes, int n_in,
                              void* d_out, int out_size, void* d_ws, size_t ws_size,
                              hipStream_t stream)
{
    const float* x  = (const float*)d_in[0];
    const float* W1 = (const float*)d_in[1];
    const float* b1 = (const float*)d_in[2];
    const float* W2 = (const float*)d_in[3];
    const float* b2 = (const float*)d_in[4];
    const float* W3 = (const float*)d_in[5];
    const float* b3 = (const float*)d_in[6];
    float* out = (float*)d_out;
    float* ws  = (float*)d_ws;       // needs 68096 bytes

    be_prep<<<1, 256, 0, stream>>>(W1, b1, W2, b2, ws);
    be_kernel<<<1024, NTHR, 0, stream>>>(x, W3, b3, ws, out);
}